// Round 2
// baseline (554.833 us; speedup 1.0000x reference)
//
#include <hip/hip_runtime.h>
#include <stdint.h>

#define NB 8
#define NPTS 100000
#define NPAD 131072          // 2^17, padded sort size per batch
#define NS 4096
#define NN 32
#define NCH 64

// d_out float layout (element offsets)
#define OUT_MAIN 0ull                          // [8,4096,32,67]
#define OUT_SRC  70254592ull                   // [8,4096,32]
#define OUT_CTR  71303168ull                   // [8,4096]
#define OUT_CF   71335936ull                   // [8,100000]
#define OUT_SF   72135936ull                   // [8,100000]

__host__ __device__ static inline uint32_t rotl32(uint32_t v, int d) {
    return (v << d) | (v >> (32 - d));
}

// JAX threefry2x32 (5 groups of 4 rounds), exact.
__host__ __device__ static inline void tf2x32(uint32_t k0, uint32_t k1,
                                              uint32_t x0, uint32_t x1,
                                              uint32_t& o0, uint32_t& o1) {
    uint32_t ks2 = k0 ^ k1 ^ 0x1BD11BDAu;
    x0 += k0; x1 += k1;
    x0 += x1; x1 = rotl32(x1, 13); x1 ^= x0;
    x0 += x1; x1 = rotl32(x1, 15); x1 ^= x0;
    x0 += x1; x1 = rotl32(x1, 26); x1 ^= x0;
    x0 += x1; x1 = rotl32(x1, 6);  x1 ^= x0;
    x0 += k1; x1 += ks2 + 1u;
    x0 += x1; x1 = rotl32(x1, 17); x1 ^= x0;
    x0 += x1; x1 = rotl32(x1, 29); x1 ^= x0;
    x0 += x1; x1 = rotl32(x1, 16); x1 ^= x0;
    x0 += x1; x1 = rotl32(x1, 24); x1 ^= x0;
    x0 += ks2; x1 += k0 + 2u;
    x0 += x1; x1 = rotl32(x1, 13); x1 ^= x0;
    x0 += x1; x1 = rotl32(x1, 15); x1 ^= x0;
    x0 += x1; x1 = rotl32(x1, 26); x1 ^= x0;
    x0 += x1; x1 = rotl32(x1, 6);  x1 ^= x0;
    x0 += k0; x1 += k1 + 3u;
    x0 += x1; x1 = rotl32(x1, 17); x1 ^= x0;
    x0 += x1; x1 = rotl32(x1, 29); x1 ^= x0;
    x0 += x1; x1 = rotl32(x1, 16); x1 ^= x0;
    x0 += x1; x1 = rotl32(x1, 24); x1 ^= x0;
    x0 += k1; x1 += ks2 + 4u;
    x0 += x1; x1 = rotl32(x1, 13); x1 ^= x0;
    x0 += x1; x1 = rotl32(x1, 15); x1 ^= x0;
    x0 += x1; x1 = rotl32(x1, 26); x1 ^= x0;
    x0 += x1; x1 = rotl32(x1, 6);  x1 ^= x0;
    x0 += ks2; x1 += k0 + 5u;
    o0 = x0; o1 = x1;
}

struct RngKeys {
    // partitionable-mode k2 keys: centers (c), neighbor draws (n)
    uint32_t c0[NB], c1[NB];
    uint32_t n0[NB], n1[NB];
};

__device__ static inline int vox1(float p) { return (int)floorf(p / 0.25f); }

// partitionable random_bits(key, 32, ...): element u -> xor of both outputs,
// counter = (hi=0, lo=u)
__device__ static inline uint32_t pbits32(uint32_t k0, uint32_t k1, uint32_t u) {
    uint32_t o0, o1;
    tf2x32(k0, k1, 0u, u, o0, o1);
    return o0 ^ o1;
}

// ---------------- kernel 0: composite keys -----------------
__global__ void k_init(const float* __restrict__ pos,
                       unsigned long long* __restrict__ comp) {
    int t = blockIdx.x * blockDim.x + threadIdx.x;   // exact grid: NB*NPAD
    int b = t >> 17, i = t & (NPAD - 1);
    unsigned long long v;
    if (i < NPTS) {
        const float* p = pos + ((size_t)b * NPTS + i) * 3;
        int vx = vox1(p[0]), vy = vox1(p[1]), vz = vox1(p[2]);
        int hk = ((vx + 512) * 1024 + (vy + 512)) * 1024 + (vz + 512);
        v = ((unsigned long long)(uint32_t)hk << 17) | (uint32_t)i;
    } else {
        v = ~0ULL;   // pad sorts to end
    }
    comp[t] = v;
}

// ---------------- bitonic sort (per-batch 2^17, unique keys => stable) ------
__global__ void k_bitonic_lds_first(unsigned long long* __restrict__ data) {
    __shared__ unsigned long long s[2048];
    int base = blockIdx.x * 2048;
    int t = threadIdx.x;                       // 1024 threads
    s[t] = data[base + t];
    s[t + 1024] = data[base + t + 1024];
    int gb = base & (NPAD - 1);                // offset within batch
    for (int k = 2; k <= 2048; k <<= 1) {
        for (int j = k >> 1; j > 0; j >>= 1) {
            __syncthreads();
            int i = ((t / j) * 2 * j) + (t % j);
            int p = i + j;
            bool up = (((gb + i) & k) == 0);
            unsigned long long a = s[i], c = s[p];
            if (up ? (a > c) : (a < c)) { s[i] = c; s[p] = a; }
        }
    }
    __syncthreads();
    data[base + t] = s[t];
    data[base + t + 1024] = s[t + 1024];
}

__global__ void k_bitonic_global(unsigned long long* __restrict__ data, int k, int j) {
    int t = blockIdx.x * blockDim.x + threadIdx.x;   // exact: NB*NPAD/2
    int b = t >> 16, u = t & (NPAD / 2 - 1);
    int i = 2 * j * (u / j) + (u % j);
    int p = i + j;
    bool up = ((i & k) == 0);
    unsigned long long* d = data + ((size_t)b << 17);
    unsigned long long a = d[i], c = d[p];
    if (up ? (a > c) : (a < c)) { d[i] = c; d[p] = a; }
}

__global__ void k_bitonic_lds_finish(unsigned long long* __restrict__ data, int k) {
    __shared__ unsigned long long s[2048];
    int base = blockIdx.x * 2048;
    int t = threadIdx.x;
    s[t] = data[base + t];
    s[t + 1024] = data[base + t + 1024];
    int gb = base & (NPAD - 1);
    bool up = ((gb & k) == 0);                 // constant per 2048-chunk (k>=4096)
    for (int j = 1024; j > 0; j >>= 1) {
        __syncthreads();
        int i = 2 * j * (t / j) + (t % j);
        int p = i + j;
        unsigned long long a = s[i], c = s[p];
        if (up ? (a > c) : (a < c)) { s[i] = c; s[p] = a; }
    }
    __syncthreads();
    data[base + t] = s[t];
    data[base + t + 1024] = s[t + 1024];
}

// ---------------- centers -----------------
__global__ void k_centers(RngKeys keys, const float* __restrict__ pos,
                          int* __restrict__ centers_ws,
                          float* __restrict__ out_ctr, float* __restrict__ out_cf) {
    int t = blockIdx.x * blockDim.x + threadIdx.x;   // exact: NB*NS
    int b = t / NS, s = t % NS;
    uint32_t lower = pbits32(keys.c0[b], keys.c1[b], (uint32_t)s);
    // randint(0,100000): multiplier = ((2^16 % span)^2 mod 2^32) % span = 0 -> lower % span
    int c = (int)(lower % 100000u);
    centers_ws[t] = c;
    out_ctr[t] = (float)c;
    out_cf[(size_t)b * NPTS + c] = 1.0f;
}

// ---------------- per-(b,s,bin) searchsorted -----------------
__device__ static inline int lbound(const unsigned long long* __restrict__ d,
                                    unsigned long long key) {
    int lo = 0, hi = NPAD;
    while (lo < hi) {
        int mid = (lo + hi) >> 1;
        if (d[mid] < key) lo = mid + 1; else hi = mid;
    }
    return lo;
}

__global__ void k_bins(const unsigned long long* __restrict__ comp,
                       const float* __restrict__ pos,
                       const int* __restrict__ centers_ws,
                       int* __restrict__ lo_ws, int* __restrict__ cnt_ws) {
    int t = blockIdx.x * blockDim.x + threadIdx.x;   // exact: NB*NS*27
    int bin = t % 27;
    int bs = t / 27;
    int b = bs / NS;
    int c = centers_ws[bs];
    const float* p = pos + ((size_t)b * NPTS + c) * 3;
    int vx = vox1(p[0]) + (bin / 9) - 1;
    int vy = vox1(p[1]) + ((bin / 3) % 3) - 1;
    int vz = vox1(p[2]) + (bin % 3) - 1;
    int hk = ((vx + 512) * 1024 + (vy + 512)) * 1024 + (vz + 512);
    const unsigned long long* d = comp + ((size_t)b << 17);
    unsigned long long keyL = ((unsigned long long)(uint32_t)hk) << 17;
    unsigned long long keyR = ((unsigned long long)(uint32_t)(hk + 1)) << 17;
    int lo = lbound(d, keyL);
    int hi = lbound(d, keyR);
    lo_ws[t] = lo;
    cnt_ws[t] = hi - lo;
}

// ---------------- cumsum over 27 bins (in place) -----------------
__global__ void k_cum(int* __restrict__ cnt_cum) {
    int t = blockIdx.x * blockDim.x + threadIdx.x;   // exact: NB*NS
    int acc = 0;
    int* a = cnt_cum + (size_t)t * 27;
    for (int i = 0; i < 27; i++) { acc += a[i]; a[i] = acc; }
}

// ---------------- neighbor selection -----------------
__global__ void k_select(RngKeys keys, const unsigned long long* __restrict__ comp,
                         const int* __restrict__ lo_ws, const int* __restrict__ cum_ws,
                         int* __restrict__ src_ws,
                         float* __restrict__ out_src, float* __restrict__ out_sf) {
    int t = blockIdx.x * blockDim.x + threadIdx.x;   // exact: NB*NS*NN
    int b = t >> 17;                                  // NS*NN = 131072
    int u = t & (NS * NN - 1);
    uint32_t lower = pbits32(keys.n0[b], keys.n1[b], (uint32_t)u);
    int bs = b * NS + (u >> 5);
    const int* cum = cum_ws + (size_t)bs * 27;
    int total = cum[26];
    int r = (int)(lower & 0x3FFFFFFFu) % total;       // span=2^30 -> multiplier=0 path
    int slot = 0, prev = 0;
    #pragma unroll
    for (int i = 0; i < 27; i++) {
        int ci = cum[i];
        if (r >= ci) { slot = i + 1; prev = ci; }
    }
    int pos_in = lo_ws[(size_t)bs * 27 + slot] + (r - prev);
    int src = (int)(comp[((size_t)b << 17) + pos_in] & 0x1FFFFu);
    src_ws[t] = src;
    out_src[t] = (float)src;
    out_sf[(size_t)b * NPTS + src] = 1.0f;
}

// ---------------- output gather: one wave per row -----------------
__global__ void k_gather(const float* __restrict__ pos, const float* __restrict__ feat,
                         const int* __restrict__ centers_ws, const int* __restrict__ src_ws,
                         float* __restrict__ out) {
    int lane = threadIdx.x & 63;
    int rloc = threadIdx.x >> 6;
    long long row = (long long)blockIdx.x * 4 + rloc;   // exact: NB*NS*NN rows
    int b = (int)(row >> 17);
    int u = (int)(row & (NS * NN - 1));
    int s = u >> 5;
    int src = src_ws[row];
    int ctr = centers_ws[b * NS + s];
    size_t obase = (size_t)row * 67;
    const float* f = feat + ((size_t)b * NPTS + src) * NCH;
    out[obase + 3 + lane] = f[lane];
    if (lane < 3) {
        out[obase + lane] = pos[((size_t)b * NPTS + src) * 3 + lane]
                          - pos[((size_t)b * NPTS + ctr) * 3 + lane];
    }
}

extern "C" void kernel_launch(void* const* d_in, const int* in_sizes, int n_in,
                              void* d_out, int out_size, void* d_ws, size_t ws_size,
                              hipStream_t stream) {
    (void)in_sizes; (void)n_in; (void)out_size; (void)ws_size;
    const float* pos = (const float*)d_in[0];
    const float* feat = (const float*)d_in[1];
    float* out = (float*)d_out;

    // ---- host-side JAX key-chain derivation (threefry PARTITIONABLE mode) ----
    // key(42) = (0,42)
    // split(key, 8):   rk_b  = tf(0,42; hi=0, lo=b)        -> (o0,o1)
    // split(rk, 2):    kc    = tf(rk;   0, 0), kn = tf(rk; 0, 1)
    // randint's k1,k2 = split(k): k2 = tf(k; 0, 1)   (only lower_bits matter)
    RngKeys keys;
    for (int b = 0; b < NB; b++) {
        uint32_t rk0, rk1, kc0, kc1, kn0, kn1;
        tf2x32(0u, 42u, 0u, (uint32_t)b, rk0, rk1);
        tf2x32(rk0, rk1, 0u, 0u, kc0, kc1);
        tf2x32(rk0, rk1, 0u, 1u, kn0, kn1);
        tf2x32(kc0, kc1, 0u, 1u, keys.c0[b], keys.c1[b]);
        tf2x32(kn0, kn1, 0u, 1u, keys.n0[b], keys.n1[b]);
    }

    // ---- workspace layout (~19.8 MB) ----
    unsigned long long* comp = (unsigned long long*)d_ws;            // NB*NPAD*8
    int* lo_ws      = (int*)((char*)d_ws + (size_t)NB * NPAD * 8);   // NB*NS*27*4
    int* cum_ws     = lo_ws + (size_t)NB * NS * 27;                  // NB*NS*27*4
    int* centers_ws = cum_ws + (size_t)NB * NS * 27;                 // NB*NS*4
    int* src_ws     = centers_ws + (size_t)NB * NS;                  // NB*NS*NN*4

    // zero the two flag outputs (contiguous 6.4 MB)
    hipMemsetAsync((char*)d_out + OUT_CF * 4, 0, (size_t)(2 * NB * NPTS) * 4, stream);

    k_init<<<(NB * NPAD) / 256, 256, 0, stream>>>(pos, comp);

    k_bitonic_lds_first<<<(NB * NPAD) / 2048, 1024, 0, stream>>>(comp);
    for (int k = 4096; k <= NPAD; k <<= 1) {
        for (int j = k >> 1; j >= 2048; j >>= 1)
            k_bitonic_global<<<(NB * NPAD / 2) / 256, 256, 0, stream>>>(comp, k, j);
        k_bitonic_lds_finish<<<(NB * NPAD) / 2048, 1024, 0, stream>>>(comp, k);
    }

    k_centers<<<(NB * NS) / 256, 256, 0, stream>>>(keys, pos, centers_ws,
                                                   out + OUT_CTR, out + OUT_CF);
    k_bins<<<(NB * NS * 27) / 256, 256, 0, stream>>>(comp, pos, centers_ws, lo_ws, cum_ws);
    k_cum<<<(NB * NS) / 256, 256, 0, stream>>>(cum_ws);
    k_select<<<(NB * NS * NN) / 256, 256, 0, stream>>>(keys, comp, lo_ws, cum_ws, src_ws,
                                                       out + OUT_SRC, out + OUT_SF);
    k_gather<<<(NB * NS * NN) / 4, 256, 0, stream>>>(pos, feat, centers_ws, src_ws, out);
}